// Round 3
// baseline (158.588 us; speedup 1.0000x reference)
//
#include <hip/hip_runtime.h>

#define NN 50000            // nodes
#define NE 800000           // edges
#define NF 128              // input features
#define NH 64               // hidden
#define NG 256              // graphs
#define NB 196              // buckets of 256 dst nodes
#define NC 196              // chunks: ceil(NE/CH)
#define CH 4096             // edges per partition block
#define CELL 80             // per-(chunk,bucket) capacity (packed 4B entries)
#define CAP 5120            // per-bucket CSR capacity
#define NGB 782             // gemm blocks: ceil(NN/64)

typedef __attribute__((ext_vector_type(8))) short bf16x8;
typedef __attribute__((ext_vector_type(4))) float f32x4;

static __device__ __forceinline__ unsigned short f2bf(float f) {
    union { float f; unsigned u; } v; v.f = f;
    unsigned r = v.u + 0x7FFF + ((v.u >> 16) & 1);   // RNE
    return (unsigned short)(r >> 16);
}
static __device__ __forceinline__ float lo16(unsigned u) {
    return __uint_as_float(u << 16);
}
static __device__ __forceinline__ float hi16(unsigned u) {
    return __uint_as_float(u & 0xFFFF0000u);
}
static __device__ __forceinline__ unsigned pack2(float a, float b) {
    return (unsigned)f2bf(a) | ((unsigned)f2bf(b) << 16);
}

// ---------------------------------------------------------------- fused: psum-zero + partition + gemm1 + W2 pack
__global__ __launch_bounds__(256) void prep_gemm(const int* __restrict__ ei,
                                                 int* __restrict__ histg,
                                                 unsigned* __restrict__ ebuf,
                                                 const float* __restrict__ X,
                                                 const float* __restrict__ W,
                                                 const float* __restrict__ W2,
                                                 unsigned short* __restrict__ Y,
                                                 float* __restrict__ psum,
                                                 unsigned* __restrict__ W2p) {
    __shared__ __align__(16) char smem[35840];
    const int t = threadIdx.x;

    if (blockIdx.x < NC) {
        // ---------------- partition path ----------------
        int* hist = (int*)smem;                    // 256
        int* incl = hist + 256;                    // 256
        int* lcur = incl + 256;                    // 256
        int* wq   = lcur + 256;                    // 4
        unsigned* lpairs = (unsigned*)(smem + 4096); // 4096 entries
        const int c = blockIdx.x;
        const int c0 = c * CH;

        hist[t] = 0;
        __syncthreads();

        int es[16], ed[16];
#pragma unroll
        for (int j = 0; j < 4; ++j) {
            const int e = c0 + (j * 256 + t) * 4;
            int4 s4 = make_int4(-1, -1, -1, -1);
            int4 d4 = make_int4(-1, -1, -1, -1);
            if (e + 3 < NE) {
                s4 = *(const int4*)&ei[e];
                d4 = *(const int4*)&ei[NE + e];
            } else {
                if (e < NE)     { s4.x = ei[e];     d4.x = ei[NE + e]; }
                if (e + 1 < NE) { s4.y = ei[e + 1]; d4.y = ei[NE + e + 1]; }
                if (e + 2 < NE) { s4.z = ei[e + 2]; d4.z = ei[NE + e + 2]; }
            }
            es[4*j] = s4.x; es[4*j+1] = s4.y; es[4*j+2] = s4.z; es[4*j+3] = s4.w;
            ed[4*j] = d4.x; ed[4*j+1] = d4.y; ed[4*j+2] = d4.z; ed[4*j+3] = d4.w;
            if (d4.x >= 0) atomicAdd(&hist[d4.x >> 8], 1);
            if (d4.y >= 0) atomicAdd(&hist[d4.y >> 8], 1);
            if (d4.z >= 0) atomicAdd(&hist[d4.z >> 8], 1);
            if (d4.w >= 0) atomicAdd(&hist[d4.w >> 8], 1);
        }
        __syncthreads();

        // shfl-based inclusive scan of hist[256] (2 barriers)
        const int v = hist[t];
        int sv = v;
#pragma unroll
        for (int off = 1; off < 64; off <<= 1) {
            int u = __shfl_up(sv, off, 64);
            if ((t & 63) >= off) sv += u;
        }
        if ((t & 63) == 63) wq[t >> 6] = sv;
        __syncthreads();
        {
            const int wid = t >> 6;
            int add = 0;
            if (wid > 0) add += wq[0];
            if (wid > 1) add += wq[1];
            if (wid > 2) add += wq[2];
            sv += add;
        }
        incl[t] = sv;
        lcur[t] = sv - v;
        if (t < NB) histg[c * NB + t] = v;
        __syncthreads();

#pragma unroll
        for (int j = 0; j < 16; ++j) {
            const int d = ed[j];
            if (d >= 0) {
                int p = atomicAdd(&lcur[d >> 8], 1);
                lpairs[p] = (unsigned)es[j] | ((unsigned)d << 16);
            }
        }
        __syncthreads();

        const int total = incl[255];
        for (int p = t; p < total; p += 256) {
            const unsigned pr = lpairs[p];
            const int b = pr >> 24;                       // dst>>8
            const int i = p - (incl[b] - hist[b]);
            ebuf[(b * NC + c) * CELL + i] = pr;
        }
    } else {
        const int gb = blockIdx.x - NC;
        if (gb >= NGB) {
            // ---------------- W2 pack path (single block) ----------------
            for (int idx = t; idx < 2048; idx += 256) {
                const int n = idx >> 5, kp = idx & 31;
                W2p[idx] = pack2(W2[(2 * kp) * 64 + n], W2[(2 * kp + 1) * 64 + n]);
            }
            return;
        }
        // ---------------- gemm1 path ----------------
        if (gb < 17) {   // zero psum (16384) + cnt (256)
            const int o = gb * 1024 + t * 4;
            if (o < 16640) *(float4*)&psum[o] = make_float4(0.f, 0.f, 0.f, 0.f);
        }

        unsigned short* Xs = (unsigned short*)smem;       // 64*136 bf16
        unsigned int* Wt = (unsigned int*)(smem + 17408); // 64*68 packed
        const int base = gb * 64;

        for (int i = t * 4; i < 64 * 128; i += 1024) {
            int node = i >> 7, k = i & 127;
            int gn = base + node; if (gn >= NN) gn = NN - 1;
            float4 v = *(const float4*)&X[(size_t)gn * 128 + k];
            ushort4 o = { f2bf(v.x), f2bf(v.y), f2bf(v.z), f2bf(v.w) };
            *(ushort4*)&Xs[node * 136 + k] = o;
        }
        for (int idx = t; idx < 64 * 64; idx += 256) {
            int n = idx & 63, kp = idx >> 6;
            float w0 = W[(2 * kp) * 64 + n];
            float w1 = W[(2 * kp + 1) * 64 + n];
            Wt[n * 68 + kp] = (unsigned)f2bf(w0) | ((unsigned)f2bf(w1) << 16);
        }
        __syncthreads();

        const int w = t >> 6;
        const int lane = t & 63;
        const int l15 = lane & 15;
        const int quad = lane >> 4;
        f32x4 acc[4] = {{0.f,0.f,0.f,0.f},{0.f,0.f,0.f,0.f},{0.f,0.f,0.f,0.f},{0.f,0.f,0.f,0.f}};
#pragma unroll
        for (int kk = 0; kk < 4; ++kk) {
            const bf16x8 a = *(const bf16x8*)&Xs[(w * 16 + l15) * 136 + quad * 8 + kk * 32];
#pragma unroll
            for (int nt = 0; nt < 4; ++nt) {
                const bf16x8 b = *(const bf16x8*)&Wt[(nt * 16 + l15) * 68 + quad * 4 + kk * 16];
                acc[nt] = __builtin_amdgcn_mfma_f32_16x16x32_bf16(a, b, acc[nt], 0, 0, 0);
            }
        }
        const int r0 = base + w * 16 + quad * 4;
#pragma unroll
        for (int reg = 0; reg < 4; ++reg) {
            const int row = r0 + reg;
            if (row < NN) {
#pragma unroll
                for (int nt = 0; nt < 4; ++nt)
                    Y[(size_t)row * 64 + nt * 16 + l15] = f2bf(acc[nt][reg]);
            }
        }
    }
}

// ---------------------------------------------------------------- level-2: per-bucket CSR + dis
__global__ __launch_bounds__(512) void build_csr(const unsigned* __restrict__ ebuf,
                                                 const int* __restrict__ histg,
                                                 int2* __restrict__ row_range,
                                                 float* __restrict__ dis,
                                                 int* __restrict__ csr_src) {
    const int b = blockIdx.x, t = threadIdx.x;
    const int e0 = b * CAP;
    __shared__ int coffs[256];
    __shared__ int cvs[256];
    __shared__ int deg_l[256];
    __shared__ int pre[256];
    __shared__ int cur[256];
    __shared__ int wq[8];
    __shared__ unsigned lpairs[CAP];
    __shared__ int lsrc[CAP];

    int cv = 0;
    if (t < NC) cv = histg[t * NB + b];
    int sv = cv;
    if (t < 256) {
#pragma unroll
        for (int off = 1; off < 64; off <<= 1) {
            int u = __shfl_up(sv, off, 64);
            if ((t & 63) >= off) sv += u;
        }
        if ((t & 63) == 63) wq[t >> 6] = sv;
        deg_l[t] = (b * 256 + t < NN) ? 1 : 0;   // self-loop
        cvs[t] = cv;
    }
    __syncthreads();
    if (t < 256) {
        const int wid = t >> 6;
        int add = 0;
        if (wid > 0) add += wq[0];
        if (wid > 1) add += wq[1];
        if (wid > 2) add += wq[2];
        coffs[t] = sv + add;
    }
    __syncthreads();

    // copy cells -> lpairs, 2 threads per cell (even/odd uint4 groups)
    {
        const int tc = t & 255;
        const int cv2 = cvs[tc];
        if (tc < NC && cv2 > 0) {
            const uint4* src4 = (const uint4*)&ebuf[(size_t)(b * NC + tc) * CELL];
            const int dst = coffs[tc] - cv2;
            for (int g4 = (t >> 8); g4 * 4 < cv2; g4 += 2) {
                const uint4 u = src4[g4];
                const int i = g4 * 4;
                lpairs[dst + i] = u.x;
                if (i + 1 < cv2) lpairs[dst + i + 1] = u.y;
                if (i + 2 < cv2) lpairs[dst + i + 2] = u.z;
                if (i + 3 < cv2) lpairs[dst + i + 3] = u.w;
            }
        }
    }
    __syncthreads();

    const int total = coffs[255];
    for (int i = t; i < total; i += 512)
        atomicAdd(&deg_l[(lpairs[i] >> 16) & 255], 1);
    __syncthreads();

    int dvi = 0, psv = 0;
    if (t < 256) {
        dvi = deg_l[t];
        psv = dvi;
#pragma unroll
        for (int off = 1; off < 64; off <<= 1) {
            int u = __shfl_up(psv, off, 64);
            if ((t & 63) >= off) psv += u;
        }
        if ((t & 63) == 63) wq[4 + (t >> 6)] = psv;
    }
    __syncthreads();
    if (t < 256) {
        const int wid = t >> 6;
        int add = 0;
        if (wid > 0) add += wq[4];
        if (wid > 1) add += wq[5];
        if (wid > 2) add += wq[6];
        psv += add;
        pre[t] = psv;
        cur[t] = 1;                        // slot 0 = self-loop
        const int nd = b * 256 + t;
        if (nd < NN) {
            const int excl = psv - dvi;
            lsrc[excl] = nd;
            row_range[nd] = make_int2(e0 + excl, e0 + psv);
            dis[nd] = rsqrtf((float)dvi);  // dvi = deg+1
        }
    }
    __syncthreads();

    for (int i = t; i < total; i += 512) {
        const unsigned p = lpairs[i];
        const int d = (p >> 16) & 255;
        const int pos = (pre[d] - deg_l[d]) + atomicAdd(&cur[d], 1);
        lsrc[pos] = (int)(p & 0xFFFFu);
    }
    __syncthreads();
    const int tot_all = pre[255];
    for (int i = t; i < tot_all; i += 512)
        csr_src[e0 + i] = lsrc[i];
}

// ---------------------------------------------------------------- gather cores (16 lanes/node, uint2, 8-deep batches)
static __device__ __forceinline__ void acc4(float* acc, const uint2 u) {
    acc[0] += lo16(u.x); acc[1] += hi16(u.x);
    acc[2] += lo16(u.y); acc[3] += hi16(u.y);
}
static __device__ __forceinline__ void fma4(float* acc, const uint2 u, const float d) {
    acc[0] = fmaf(lo16(u.x), d, acc[0]); acc[1] = fmaf(hi16(u.x), d, acc[1]);
    acc[2] = fmaf(lo16(u.y), d, acc[2]); acc[3] = fmaf(hi16(u.y), d, acc[3]);
}

// pre-scaled rows (layer 2)
static __device__ __forceinline__ void gather16(const unsigned short* __restrict__ h,
                                                const int* __restrict__ csr,
                                                int lo, int hi, int p4, float* acc) {
    int i = lo;
    for (; i + 8 <= hi; i += 8) {
        int idx[8];
#pragma unroll
        for (int j = 0; j < 8; ++j) idx[j] = csr[i + j];
        uint2 u[8];
#pragma unroll
        for (int j = 0; j < 8; ++j) u[j] = *(const uint2*)&h[(idx[j] << 6) + p4];
#pragma unroll
        for (int j = 0; j < 8; ++j) acc4(acc, u[j]);
    }
    if (i + 4 <= hi) {
        int idx[4];
#pragma unroll
        for (int j = 0; j < 4; ++j) idx[j] = csr[i + j];
#pragma unroll
        for (int j = 0; j < 4; ++j) acc4(acc, *(const uint2*)&h[(idx[j] << 6) + p4]);
        i += 4;
    }
    if (i + 2 <= hi) {
        const int i0 = csr[i], i1 = csr[i + 1];
        const uint2 u0 = *(const uint2*)&h[(i0 << 6) + p4];
        const uint2 u1 = *(const uint2*)&h[(i1 << 6) + p4];
        acc4(acc, u0); acc4(acc, u1);
        i += 2;
    }
    if (i < hi) acc4(acc, *(const uint2*)&h[(csr[i] << 6) + p4]);
}

// unscaled rows (layer 1): fold dis[src] at accumulate time
static __device__ __forceinline__ void gather16_scaled(const unsigned short* __restrict__ h,
                                                       const int* __restrict__ csr,
                                                       const float* __restrict__ dis,
                                                       int lo, int hi, int p4, float* acc) {
    int i = lo;
    for (; i + 8 <= hi; i += 8) {
        int idx[8];
#pragma unroll
        for (int j = 0; j < 8; ++j) idx[j] = csr[i + j];
        float d[8];
#pragma unroll
        for (int j = 0; j < 8; ++j) d[j] = dis[idx[j]];
        uint2 u[8];
#pragma unroll
        for (int j = 0; j < 8; ++j) u[j] = *(const uint2*)&h[(idx[j] << 6) + p4];
#pragma unroll
        for (int j = 0; j < 8; ++j) fma4(acc, u[j], d[j]);
    }
    if (i + 4 <= hi) {
        int idx[4];
#pragma unroll
        for (int j = 0; j < 4; ++j) idx[j] = csr[i + j];
        float d[4];
#pragma unroll
        for (int j = 0; j < 4; ++j) d[j] = dis[idx[j]];
#pragma unroll
        for (int j = 0; j < 4; ++j) fma4(acc, *(const uint2*)&h[(idx[j] << 6) + p4], d[j]);
        i += 4;
    }
    if (i + 2 <= hi) {
        const int i0 = csr[i], i1 = csr[i + 1];
        const float d0 = dis[i0], d1 = dis[i1];
        const uint2 u0 = *(const uint2*)&h[(i0 << 6) + p4];
        const uint2 u1 = *(const uint2*)&h[(i1 << 6) + p4];
        fma4(acc, u0, d0); fma4(acc, u1, d1);
        i += 2;
    }
    if (i < hi) {
        const int i0 = csr[i];
        fma4(acc, *(const uint2*)&h[(i0 << 6) + p4], dis[i0]);
    }
}

// ---------------------------------------------------------------- agg1 + gemm2 fused (512 thr, 16 lanes/node)
__global__ __launch_bounds__(512) void agg_gemv(const unsigned short* __restrict__ h,
                                                const int2* __restrict__ row_range,
                                                const int* __restrict__ csr_src,
                                                const float* __restrict__ dis,
                                                const float* __restrict__ b1,
                                                const unsigned* __restrict__ W2p,
                                                unsigned short* __restrict__ g) {
    __shared__ unsigned short W2b[64 * 72];  // [n][k] bf16
    __shared__ unsigned short A[32 * 72];    // [m=node][k=dim] bf16
    const int t = threadIdx.x;
    const int base = blockIdx.x * 32;
    const int nloc = t >> 4;
    const int p4 = (t & 15) * 4;
    const int n = base + nloc;
    float acc[4] = {};
    if (n < NN) {
        const int2 rr = row_range[n];
        gather16_scaled(h, csr_src, dis, rr.x, rr.y, p4, acc);
        const float dn = dis[n];
        const float4 bv = *(const float4*)&b1[p4];
        acc[0] = fmaxf(acc[0] * dn + bv.x, 0.f);
        acc[1] = fmaxf(acc[1] * dn + bv.y, 0.f);
        acc[2] = fmaxf(acc[2] * dn + bv.z, 0.f);
        acc[3] = fmaxf(acc[3] * dn + bv.w, 0.f);
    }
    for (int idx = t; idx < 2048; idx += 512) {   // stage W2 after gather (don't stall gather issue)
        const int nn2 = idx >> 5, kp = idx & 31;
        *(unsigned*)&W2b[nn2 * 72 + 2 * kp] = W2p[idx];
    }
    uint2 pk;
    pk.x = pack2(acc[0], acc[1]);
    pk.y = pack2(acc[2], acc[3]);
    *(uint2*)&A[nloc * 72 + p4] = pk;
    __syncthreads();

    const int w = t >> 6;          // 8 waves: mt = w&1, ncol = w>>1
    const int lane = t & 63;
    const int l15 = lane & 15;
    const int quad = lane >> 4;
    const int mt = w & 1;
    const int ncol = w >> 1;
    const bf16x8 a0 = *(const bf16x8*)&A[(mt * 16 + l15) * 72 + quad * 8];
    const bf16x8 a1 = *(const bf16x8*)&A[(mt * 16 + l15) * 72 + 32 + quad * 8];
    const bf16x8 bb0 = *(const bf16x8*)&W2b[(ncol * 16 + l15) * 72 + quad * 8];
    const bf16x8 bb1 = *(const bf16x8*)&W2b[(ncol * 16 + l15) * 72 + 32 + quad * 8];
    f32x4 c = {0.f, 0.f, 0.f, 0.f};
    c = __builtin_amdgcn_mfma_f32_16x16x32_bf16(a0, bb0, c, 0, 0, 0);
    c = __builtin_amdgcn_mfma_f32_16x16x32_bf16(a1, bb1, c, 0, 0, 0);
    const int r0 = base + mt * 16 + quad * 4;
    float4 d4 = *(const float4*)&dis[r0];   // tail over-read; stores guarded
    const float dd[4] = { d4.x, d4.y, d4.z, d4.w };
#pragma unroll
    for (int reg = 0; reg < 4; ++reg) {
        const int row = r0 + reg;
        if (row < NN)
            g[(size_t)row * 64 + ncol * 16 + l15] = f2bf(c[reg] * dd[reg]);
    }
}

// ---------------------------------------------------------------- agg2 + pooling fused (512 thr) + graph counts
__global__ __launch_bounds__(512) void agg_pool(const unsigned short* __restrict__ h,
                                                const int2* __restrict__ row_range,
                                                const int* __restrict__ csr_src,
                                                const float* __restrict__ dis,
                                                const float* __restrict__ bias,
                                                const int* __restrict__ batch,
                                                float* __restrict__ psum,
                                                float* __restrict__ cnt) {
    __shared__ float rowsL[32 * 68];
    __shared__ int nb[32];
    const int t = threadIdx.x;
    const int nloc = t >> 4;
    const int n = blockIdx.x * 32 + nloc;
    const int p4 = (t & 15) * 4;
    if ((t & 15) == 0) nb[nloc] = (n < NN) ? batch[n] : -1;
    if (n < NN) {
        const int2 rr = row_range[n];
        float acc[4] = {};
        gather16(h, csr_src, rr.x, rr.y, p4, acc);
        const float dn = dis[n];
        const float4 bv = *(const float4*)&bias[p4];
        float4 r;
        r.x = fmaxf(acc[0] * dn + bv.x, 0.f);
        r.y = fmaxf(acc[1] * dn + bv.y, 0.f);
        r.z = fmaxf(acc[2] * dn + bv.z, 0.f);
        r.w = fmaxf(acc[3] * dn + bv.w, 0.f);
        *(float4*)&rowsL[nloc * 68 + p4] = r;
    }
    __syncthreads();
    if (t < 64) {
        float s = 0.f; int curg = -2; int rl = 0;
        for (int r = 0; r < 32; ++r) {
            const int gg = nb[r];                 // wave-uniform
            if (gg != curg) {
                if (curg >= 0) {
                    atomicAdd(&psum[curg * 64 + t], s);
                    if (t == 0) atomicAdd(&cnt[curg], (float)rl);
                }
                s = 0.f; rl = 0; curg = gg;
            }
            if (gg >= 0) { s += rowsL[r * 68 + t]; ++rl; }
        }
        if (curg >= 0) {
            atomicAdd(&psum[curg * 64 + t], s);
            if (t == 0) atomicAdd(&cnt[curg], (float)rl);
        }
    }
}

// ---------------------------------------------------------------- head: mean + MLP (no binary search)
__global__ __launch_bounds__(64) void head_kernel(const float* __restrict__ psum,
                                                  const float* __restrict__ cnt,
                                                  const float* __restrict__ Wm1,
                                                  const float* __restrict__ bm1,
                                                  const float* __restrict__ Wm2,
                                                  const float* __restrict__ bm2,
                                                  float* __restrict__ out) {
    const int g = blockIdx.x;
    const int t = threadIdx.x;
    __shared__ float pl[64];
    const float inv = 1.f / fmaxf(cnt[g], 1.f);
    pl[t] = psum[g * 64 + t] * inv;
    __syncthreads();
    float z = bm1[t];
#pragma unroll 8
    for (int k = 0; k < 64; ++k)
        z += pl[k] * Wm1[k * 64 + t];
    z = fmaxf(z, 0.f);
    float y = z * Wm2[t];
    for (int off = 32; off; off >>= 1) y += __shfl_down(y, off);
    if (t == 0) out[g] = y + bm2[0];
}

// ---------------------------------------------------------------- launch
extern "C" void kernel_launch(void* const* d_in, const int* in_sizes, int n_in,
                              void* d_out, int out_size, void* d_ws, size_t ws_size,
                              hipStream_t stream) {
    const float* x   = (const float*)d_in[0];
    const int*   ei  = (const int*)d_in[1];
    const int*   bat = (const int*)d_in[2];
    const float* W1  = (const float*)d_in[3];
    const float* b1  = (const float*)d_in[4];
    const float* W2  = (const float*)d_in[5];
    const float* b2  = (const float*)d_in[6];
    const float* Wm1 = (const float*)d_in[7];
    const float* bm1 = (const float*)d_in[8];
    const float* Wm2 = (const float*)d_in[9];
    const float* bm2 = (const float*)d_in[10];
    float* out = (float*)d_out;

    char* w = (char*)d_ws;
    int*            histg     = (int*)           (w + 0);          //   153664 B
    int2*           row_range = (int2*)          (w + 153664);     //   400000 B
    float*          dis       = (float*)         (w + 553664);     //   200000 B
    int*            csr_src   = (int*)           (w + 753664);     //  4014080 B
    unsigned*       ebuf      = (unsigned*)      (w + 4767744);    // 12293120 B (packed 4B edges)
    unsigned short* bufA      = (unsigned short*)(w + 17060864);   //  6400000 B
    unsigned short* bufB      = (unsigned short*)(w + 23460864);   //  6400000 B
    float*          psum      = (float*)         (w + 29860864);   //    66560 B (16384 psum + 256 cnt)
    unsigned*       W2p       = (unsigned*)      (w + 29927424);   //     8192 B
    float*          cnt       = psum + 16384;

    prep_gemm <<<NC + NGB + 1, 256, 0, stream>>>(ei, histg, ebuf, x, W1, W2, bufA, psum, W2p);
    build_csr <<<NB, 512, 0, stream>>>(ebuf, histg, row_range, dis, csr_src);
    agg_gemv  <<<(NN + 31) / 32, 512, 0, stream>>>(bufA, row_range, csr_src, dis, b1, W2p, bufB);
    agg_pool  <<<(NN + 31) / 32, 512, 0, stream>>>(bufB, row_range, csr_src, dis, b2, bat, psum, cnt);
    head_kernel<<<NG, 64, 0, stream>>>(psum, cnt, Wm1, bm1, Wm2, bm2, out);
}

// Round 4
// 149.226 us; speedup vs baseline: 1.0627x; 1.0627x over previous
//
#include <hip/hip_runtime.h>

#define NN 50000            // nodes
#define NE 800000           // edges
#define NF 128              // input features
#define NH 64               // hidden
#define NG 256              // graphs
#define NB 196              // buckets of 256 dst nodes
#define NC 196              // chunks: ceil(NE/CH)
#define CH 4096             // edges per partition block
#define CELL 80             // per-(chunk,bucket) capacity (packed 4B entries)
#define CAP 5120            // per-bucket CSR capacity
#define NGB 782             // gemm blocks: ceil(NN/64)

typedef __attribute__((ext_vector_type(8))) short bf16x8;
typedef __attribute__((ext_vector_type(4))) float f32x4;

static __device__ __forceinline__ unsigned short f2bf(float f) {
    union { float f; unsigned u; } v; v.f = f;
    unsigned r = v.u + 0x7FFF + ((v.u >> 16) & 1);   // RNE
    return (unsigned short)(r >> 16);
}
static __device__ __forceinline__ float lo16(unsigned u) {
    return __uint_as_float(u << 16);
}
static __device__ __forceinline__ float hi16(unsigned u) {
    return __uint_as_float(u & 0xFFFF0000u);
}
static __device__ __forceinline__ unsigned pack2(float a, float b) {
    return (unsigned)f2bf(a) | ((unsigned)f2bf(b) << 16);
}

// ---------------------------------------------------------------- fused: psum-zero + partition + gemm1 + W2 pack
__global__ __launch_bounds__(256) void prep_gemm(const int* __restrict__ ei,
                                                 int* __restrict__ histg,
                                                 unsigned* __restrict__ ebuf,
                                                 const float* __restrict__ X,
                                                 const float* __restrict__ W,
                                                 const float* __restrict__ W2,
                                                 unsigned short* __restrict__ Y,
                                                 float* __restrict__ psum,
                                                 unsigned* __restrict__ W2p) {
    __shared__ __align__(16) char smem[35840];
    const int t = threadIdx.x;

    if (blockIdx.x < NC) {
        // ---------------- partition path ----------------
        int* hist = (int*)smem;                    // 256
        int* incl = hist + 256;                    // 256
        int* lcur = incl + 256;                    // 256
        int* wq   = lcur + 256;                    // 4
        unsigned* lpairs = (unsigned*)(smem + 4096); // 4096 entries
        const int c = blockIdx.x;
        const int c0 = c * CH;

        hist[t] = 0;
        __syncthreads();

        int es[16], ed[16];
#pragma unroll
        for (int j = 0; j < 4; ++j) {
            const int e = c0 + (j * 256 + t) * 4;
            int4 s4 = make_int4(-1, -1, -1, -1);
            int4 d4 = make_int4(-1, -1, -1, -1);
            if (e + 3 < NE) {
                s4 = *(const int4*)&ei[e];
                d4 = *(const int4*)&ei[NE + e];
            } else {
                if (e < NE)     { s4.x = ei[e];     d4.x = ei[NE + e]; }
                if (e + 1 < NE) { s4.y = ei[e + 1]; d4.y = ei[NE + e + 1]; }
                if (e + 2 < NE) { s4.z = ei[e + 2]; d4.z = ei[NE + e + 2]; }
            }
            es[4*j] = s4.x; es[4*j+1] = s4.y; es[4*j+2] = s4.z; es[4*j+3] = s4.w;
            ed[4*j] = d4.x; ed[4*j+1] = d4.y; ed[4*j+2] = d4.z; ed[4*j+3] = d4.w;
            if (d4.x >= 0) atomicAdd(&hist[d4.x >> 8], 1);
            if (d4.y >= 0) atomicAdd(&hist[d4.y >> 8], 1);
            if (d4.z >= 0) atomicAdd(&hist[d4.z >> 8], 1);
            if (d4.w >= 0) atomicAdd(&hist[d4.w >> 8], 1);
        }
        __syncthreads();

        // shfl-based inclusive scan of hist[256] (2 barriers)
        const int v = hist[t];
        int sv = v;
#pragma unroll
        for (int off = 1; off < 64; off <<= 1) {
            int u = __shfl_up(sv, off, 64);
            if ((t & 63) >= off) sv += u;
        }
        if ((t & 63) == 63) wq[t >> 6] = sv;
        __syncthreads();
        {
            const int wid = t >> 6;
            int add = 0;
            if (wid > 0) add += wq[0];
            if (wid > 1) add += wq[1];
            if (wid > 2) add += wq[2];
            sv += add;
        }
        incl[t] = sv;
        lcur[t] = sv - v;
        if (t < NB) histg[c * NB + t] = v;
        __syncthreads();

#pragma unroll
        for (int j = 0; j < 16; ++j) {
            const int d = ed[j];
            if (d >= 0) {
                int p = atomicAdd(&lcur[d >> 8], 1);
                lpairs[p] = (unsigned)es[j] | ((unsigned)d << 16);
            }
        }
        __syncthreads();

        const int total = incl[255];
        for (int p = t; p < total; p += 256) {
            const unsigned pr = lpairs[p];
            const int b = pr >> 24;                       // dst>>8
            const int i = p - (incl[b] - hist[b]);
            ebuf[(b * NC + c) * CELL + i] = pr;
        }
    } else {
        const int gb = blockIdx.x - NC;
        if (gb >= NGB) {
            // ---------------- W2 pack path (single block) ----------------
            for (int idx = t; idx < 2048; idx += 256) {
                const int n = idx >> 5, kp = idx & 31;
                W2p[idx] = pack2(W2[(2 * kp) * 64 + n], W2[(2 * kp + 1) * 64 + n]);
            }
            return;
        }
        // ---------------- gemm1 path ----------------
        if (gb < 17) {   // zero psum (16384) + cnt (256)
            const int o = gb * 1024 + t * 4;
            if (o < 16640) *(float4*)&psum[o] = make_float4(0.f, 0.f, 0.f, 0.f);
        }

        unsigned short* Xs = (unsigned short*)smem;       // 64*136 bf16
        unsigned int* Wt = (unsigned int*)(smem + 17408); // 64*68 packed
        const int base = gb * 64;

        for (int i = t * 4; i < 64 * 128; i += 1024) {
            int node = i >> 7, k = i & 127;
            int gn = base + node; if (gn >= NN) gn = NN - 1;
            float4 v = *(const float4*)&X[(size_t)gn * 128 + k];
            ushort4 o = { f2bf(v.x), f2bf(v.y), f2bf(v.z), f2bf(v.w) };
            *(ushort4*)&Xs[node * 136 + k] = o;
        }
        for (int idx = t; idx < 64 * 64; idx += 256) {
            int n = idx & 63, kp = idx >> 6;
            float w0 = W[(2 * kp) * 64 + n];
            float w1 = W[(2 * kp + 1) * 64 + n];
            Wt[n * 68 + kp] = (unsigned)f2bf(w0) | ((unsigned)f2bf(w1) << 16);
        }
        __syncthreads();

        const int w = t >> 6;
        const int lane = t & 63;
        const int l15 = lane & 15;
        const int quad = lane >> 4;
        f32x4 acc[4] = {{0.f,0.f,0.f,0.f},{0.f,0.f,0.f,0.f},{0.f,0.f,0.f,0.f},{0.f,0.f,0.f,0.f}};
#pragma unroll
        for (int kk = 0; kk < 4; ++kk) {
            const bf16x8 a = *(const bf16x8*)&Xs[(w * 16 + l15) * 136 + quad * 8 + kk * 32];
#pragma unroll
            for (int nt = 0; nt < 4; ++nt) {
                const bf16x8 b = *(const bf16x8*)&Wt[(nt * 16 + l15) * 68 + quad * 4 + kk * 16];
                acc[nt] = __builtin_amdgcn_mfma_f32_16x16x32_bf16(a, b, acc[nt], 0, 0, 0);
            }
        }
        const int r0 = base + w * 16 + quad * 4;
#pragma unroll
        for (int reg = 0; reg < 4; ++reg) {
            const int row = r0 + reg;
            if (row < NN) {
#pragma unroll
                for (int nt = 0; nt < 4; ++nt)
                    Y[(size_t)row * 64 + nt * 16 + l15] = f2bf(acc[nt][reg]);
            }
        }
    }
}

// ---------------------------------------------------------------- level-2: per-bucket CSR + dis
__global__ __launch_bounds__(512) void build_csr(const unsigned* __restrict__ ebuf,
                                                 const int* __restrict__ histg,
                                                 int2* __restrict__ row_range,
                                                 float* __restrict__ dis,
                                                 int* __restrict__ csr_src) {
    const int b = blockIdx.x, t = threadIdx.x;
    const int e0 = b * CAP;
    __shared__ int coffs[256];
    __shared__ int cvs[256];
    __shared__ int deg_l[256];
    __shared__ int pre[256];
    __shared__ int cur[256];
    __shared__ int wq[8];
    __shared__ unsigned lpairs[CAP];
    __shared__ int lsrc[CAP];

    int cv = 0;
    if (t < NC) cv = histg[t * NB + b];
    int sv = cv;
    if (t < 256) {
#pragma unroll
        for (int off = 1; off < 64; off <<= 1) {
            int u = __shfl_up(sv, off, 64);
            if ((t & 63) >= off) sv += u;
        }
        if ((t & 63) == 63) wq[t >> 6] = sv;
        deg_l[t] = (b * 256 + t < NN) ? 1 : 0;   // self-loop
        cvs[t] = cv;
    }
    __syncthreads();
    if (t < 256) {
        const int wid = t >> 6;
        int add = 0;
        if (wid > 0) add += wq[0];
        if (wid > 1) add += wq[1];
        if (wid > 2) add += wq[2];
        coffs[t] = sv + add;
    }
    __syncthreads();

    // copy cells -> lpairs, 2 threads per cell (even/odd uint4 groups)
    {
        const int tc = t & 255;
        const int cv2 = cvs[tc];
        if (tc < NC && cv2 > 0) {
            const uint4* src4 = (const uint4*)&ebuf[(size_t)(b * NC + tc) * CELL];
            const int dst = coffs[tc] - cv2;
            for (int g4 = (t >> 8); g4 * 4 < cv2; g4 += 2) {
                const uint4 u = src4[g4];
                const int i = g4 * 4;
                lpairs[dst + i] = u.x;
                if (i + 1 < cv2) lpairs[dst + i + 1] = u.y;
                if (i + 2 < cv2) lpairs[dst + i + 2] = u.z;
                if (i + 3 < cv2) lpairs[dst + i + 3] = u.w;
            }
        }
    }
    __syncthreads();

    const int total = coffs[255];
    for (int i = t; i < total; i += 512)
        atomicAdd(&deg_l[(lpairs[i] >> 16) & 255], 1);
    __syncthreads();

    int dvi = 0, psv = 0;
    if (t < 256) {
        dvi = deg_l[t];
        psv = dvi;
#pragma unroll
        for (int off = 1; off < 64; off <<= 1) {
            int u = __shfl_up(psv, off, 64);
            if ((t & 63) >= off) psv += u;
        }
        if ((t & 63) == 63) wq[4 + (t >> 6)] = psv;
    }
    __syncthreads();
    if (t < 256) {
        const int wid = t >> 6;
        int add = 0;
        if (wid > 0) add += wq[4];
        if (wid > 1) add += wq[5];
        if (wid > 2) add += wq[6];
        psv += add;
        pre[t] = psv;
        cur[t] = 1;                        // slot 0 = self-loop
        const int nd = b * 256 + t;
        if (nd < NN) {
            const int excl = psv - dvi;
            lsrc[excl] = nd;
            row_range[nd] = make_int2(e0 + excl, e0 + psv);
            dis[nd] = rsqrtf((float)dvi);  // dvi = deg+1
        }
    }
    __syncthreads();

    for (int i = t; i < total; i += 512) {
        const unsigned p = lpairs[i];
        const int d = (p >> 16) & 255;
        const int pos = (pre[d] - deg_l[d]) + atomicAdd(&cur[d], 1);
        lsrc[pos] = (int)(p & 0xFFFFu);
    }
    __syncthreads();
    const int tot_all = pre[255];
    for (int i = t; i < tot_all; i += 512)
        csr_src[e0 + i] = lsrc[i];
}

// ---------------------------------------------------------------- gather cores (8 lanes/node, uint4, 8-deep batches)
static __device__ __forceinline__ void acc8(float* acc, const uint4 u) {
    acc[0] += lo16(u.x); acc[1] += hi16(u.x);
    acc[2] += lo16(u.y); acc[3] += hi16(u.y);
    acc[4] += lo16(u.z); acc[5] += hi16(u.z);
    acc[6] += lo16(u.w); acc[7] += hi16(u.w);
}
static __device__ __forceinline__ void fma8(float* acc, const uint4 u, const float d) {
    acc[0] = fmaf(lo16(u.x), d, acc[0]); acc[1] = fmaf(hi16(u.x), d, acc[1]);
    acc[2] = fmaf(lo16(u.y), d, acc[2]); acc[3] = fmaf(hi16(u.y), d, acc[3]);
    acc[4] = fmaf(lo16(u.z), d, acc[4]); acc[5] = fmaf(hi16(u.z), d, acc[5]);
    acc[6] = fmaf(lo16(u.w), d, acc[6]); acc[7] = fmaf(hi16(u.w), d, acc[7]);
}

// pre-scaled rows (layer 2): 8-deep dependent batches
static __device__ __forceinline__ void gather_rows(const unsigned short* __restrict__ h,
                                                   const int* __restrict__ csr,
                                                   int lo, int hi, int p8, float* acc) {
    int i = lo;
    for (; i + 8 <= hi; i += 8) {
        int idx[8];
#pragma unroll
        for (int j = 0; j < 8; ++j) idx[j] = csr[i + j];
        uint4 u[8];
#pragma unroll
        for (int j = 0; j < 8; ++j) u[j] = *(const uint4*)&h[(idx[j] << 6) + p8];
#pragma unroll
        for (int j = 0; j < 8; ++j) acc8(acc, u[j]);
    }
    if (i + 4 <= hi) {
        int idx[4];
#pragma unroll
        for (int j = 0; j < 4; ++j) idx[j] = csr[i + j];
        uint4 u[4];
#pragma unroll
        for (int j = 0; j < 4; ++j) u[j] = *(const uint4*)&h[(idx[j] << 6) + p8];
#pragma unroll
        for (int j = 0; j < 4; ++j) acc8(acc, u[j]);
        i += 4;
    }
    if (i + 2 <= hi) {
        const int i0 = csr[i], i1 = csr[i + 1];
        const uint4 u0 = *(const uint4*)&h[(i0 << 6) + p8];
        const uint4 u1 = *(const uint4*)&h[(i1 << 6) + p8];
        acc8(acc, u0); acc8(acc, u1);
        i += 2;
    }
    if (i < hi) acc8(acc, *(const uint4*)&h[(csr[i] << 6) + p8]);
}

// unscaled rows (layer 1): fold dis[src] at accumulate time, 8-deep batches
static __device__ __forceinline__ void gather_rows_scaled(const unsigned short* __restrict__ h,
                                                          const int* __restrict__ csr,
                                                          const float* __restrict__ dis,
                                                          int lo, int hi, int p8, float* acc) {
    int i = lo;
    for (; i + 8 <= hi; i += 8) {
        int idx[8];
#pragma unroll
        for (int j = 0; j < 8; ++j) idx[j] = csr[i + j];
        float d[8];
#pragma unroll
        for (int j = 0; j < 8; ++j) d[j] = dis[idx[j]];
        uint4 u[8];
#pragma unroll
        for (int j = 0; j < 8; ++j) u[j] = *(const uint4*)&h[(idx[j] << 6) + p8];
#pragma unroll
        for (int j = 0; j < 8; ++j) fma8(acc, u[j], d[j]);
    }
    if (i + 4 <= hi) {
        int idx[4];
#pragma unroll
        for (int j = 0; j < 4; ++j) idx[j] = csr[i + j];
        float d[4];
#pragma unroll
        for (int j = 0; j < 4; ++j) d[j] = dis[idx[j]];
        uint4 u[4];
#pragma unroll
        for (int j = 0; j < 4; ++j) u[j] = *(const uint4*)&h[(idx[j] << 6) + p8];
#pragma unroll
        for (int j = 0; j < 4; ++j) fma8(acc, u[j], d[j]);
        i += 4;
    }
    if (i + 2 <= hi) {
        const int i0 = csr[i], i1 = csr[i + 1];
        const float d0 = dis[i0], d1 = dis[i1];
        const uint4 u0 = *(const uint4*)&h[(i0 << 6) + p8];
        const uint4 u1 = *(const uint4*)&h[(i1 << 6) + p8];
        fma8(acc, u0, d0); fma8(acc, u1, d1);
        i += 2;
    }
    if (i < hi) {
        const int i0 = csr[i];
        fma8(acc, *(const uint4*)&h[(i0 << 6) + p8], dis[i0]);
    }
}

// ---------------------------------------------------------------- agg1 + gemm2 fused (256 thr, 8 lanes/node)
__global__ __launch_bounds__(256) void agg_gemv(const unsigned short* __restrict__ h,
                                                const int2* __restrict__ row_range,
                                                const int* __restrict__ csr_src,
                                                const float* __restrict__ dis,
                                                const float* __restrict__ b1,
                                                const unsigned* __restrict__ W2p,
                                                unsigned short* __restrict__ g) {
    __shared__ unsigned short W2b[64 * 72];  // [n][k] bf16
    __shared__ unsigned short A[32 * 72];    // [m=node][k=dim] bf16
    const int t = threadIdx.x;
    const int base = blockIdx.x * 32;
    const int nloc = t >> 3;
    const int p8 = (t & 7) * 8;
    const int n = base + nloc;
    float acc[8] = {};
    if (n < NN) {
        const int2 rr = row_range[n];
        gather_rows_scaled(h, csr_src, dis, rr.x, rr.y, p8, acc);
        const float dn = dis[n];
        const float4 bv0 = *(const float4*)&b1[p8];
        const float4 bv1 = *(const float4*)&b1[p8 + 4];
        acc[0] = fmaxf(acc[0] * dn + bv0.x, 0.f);
        acc[1] = fmaxf(acc[1] * dn + bv0.y, 0.f);
        acc[2] = fmaxf(acc[2] * dn + bv0.z, 0.f);
        acc[3] = fmaxf(acc[3] * dn + bv0.w, 0.f);
        acc[4] = fmaxf(acc[4] * dn + bv1.x, 0.f);
        acc[5] = fmaxf(acc[5] * dn + bv1.y, 0.f);
        acc[6] = fmaxf(acc[6] * dn + bv1.z, 0.f);
        acc[7] = fmaxf(acc[7] * dn + bv1.w, 0.f);
    }
    for (int idx = t; idx < 2048; idx += 256) {   // stage W2 after gather (loads are independent)
        const int nn2 = idx >> 5, kp = idx & 31;
        *(unsigned*)&W2b[nn2 * 72 + 2 * kp] = W2p[idx];
    }
    uint4 pk;
    pk.x = pack2(acc[0], acc[1]);
    pk.y = pack2(acc[2], acc[3]);
    pk.z = pack2(acc[4], acc[5]);
    pk.w = pack2(acc[6], acc[7]);
    *(uint4*)&A[nloc * 72 + p8] = pk;
    __syncthreads();

    const int w = t >> 6;
    const int lane = t & 63;
    const int l15 = lane & 15;
    const int quad = lane >> 4;
    const int mt = w & 1;
    const int nq = (w >> 1) * 2;
    const bf16x8 a0 = *(const bf16x8*)&A[(mt * 16 + l15) * 72 + quad * 8];
    const bf16x8 a1 = *(const bf16x8*)&A[(mt * 16 + l15) * 72 + 32 + quad * 8];
    const bf16x8 b00 = *(const bf16x8*)&W2b[(nq * 16 + l15) * 72 + quad * 8];
    const bf16x8 b01 = *(const bf16x8*)&W2b[(nq * 16 + l15) * 72 + 32 + quad * 8];
    const bf16x8 b10 = *(const bf16x8*)&W2b[((nq + 1) * 16 + l15) * 72 + quad * 8];
    const bf16x8 b11 = *(const bf16x8*)&W2b[((nq + 1) * 16 + l15) * 72 + 32 + quad * 8];
    f32x4 c0 = {0.f, 0.f, 0.f, 0.f}, c1 = {0.f, 0.f, 0.f, 0.f};
    c0 = __builtin_amdgcn_mfma_f32_16x16x32_bf16(a0, b00, c0, 0, 0, 0);
    c0 = __builtin_amdgcn_mfma_f32_16x16x32_bf16(a1, b01, c0, 0, 0, 0);
    c1 = __builtin_amdgcn_mfma_f32_16x16x32_bf16(a0, b10, c1, 0, 0, 0);
    c1 = __builtin_amdgcn_mfma_f32_16x16x32_bf16(a1, b11, c1, 0, 0, 0);
    const int r0 = base + mt * 16 + quad * 4;
    float4 d4 = *(const float4*)&dis[r0];   // tail over-read; stores guarded
    const float dd[4] = { d4.x, d4.y, d4.z, d4.w };
#pragma unroll
    for (int reg = 0; reg < 4; ++reg) {
        const int row = r0 + reg;
        if (row < NN) {
            g[(size_t)row * 64 + nq * 16 + l15] = f2bf(c0[reg] * dd[reg]);
            g[(size_t)row * 64 + (nq + 1) * 16 + l15] = f2bf(c1[reg] * dd[reg]);
        }
    }
}

// ---------------------------------------------------------------- agg2 + pooling fused (256 thr, 8 lanes/node) + graph counts
__global__ __launch_bounds__(256) void agg_pool(const unsigned short* __restrict__ h,
                                                const int2* __restrict__ row_range,
                                                const int* __restrict__ csr_src,
                                                const float* __restrict__ dis,
                                                const float* __restrict__ bias,
                                                const int* __restrict__ batch,
                                                float* __restrict__ psum,
                                                float* __restrict__ cnt) {
    __shared__ float rowsL[32 * 68];
    __shared__ int nb[32];
    const int t = threadIdx.x;
    const int nloc = t >> 3;
    const int n = blockIdx.x * 32 + nloc;
    const int p8 = (t & 7) * 8;
    if ((t & 7) == 0) nb[nloc] = (n < NN) ? batch[n] : -1;
    if (n < NN) {
        const int2 rr = row_range[n];
        float acc[8] = {};
        gather_rows(h, csr_src, rr.x, rr.y, p8, acc);
        const float dn = dis[n];
        const float4 bv0 = *(const float4*)&bias[p8];
        const float4 bv1 = *(const float4*)&bias[p8 + 4];
        float4 r0, r1;
        r0.x = fmaxf(acc[0] * dn + bv0.x, 0.f);
        r0.y = fmaxf(acc[1] * dn + bv0.y, 0.f);
        r0.z = fmaxf(acc[2] * dn + bv0.z, 0.f);
        r0.w = fmaxf(acc[3] * dn + bv0.w, 0.f);
        r1.x = fmaxf(acc[4] * dn + bv1.x, 0.f);
        r1.y = fmaxf(acc[5] * dn + bv1.y, 0.f);
        r1.z = fmaxf(acc[6] * dn + bv1.z, 0.f);
        r1.w = fmaxf(acc[7] * dn + bv1.w, 0.f);
        *(float4*)&rowsL[nloc * 68 + p8] = r0;
        *(float4*)&rowsL[nloc * 68 + p8 + 4] = r1;
    }
    __syncthreads();
    if (t < 64) {
        float s = 0.f; int curg = -2; int rl = 0;
        for (int r = 0; r < 32; ++r) {
            const int gg = nb[r];                 // wave-uniform
            if (gg != curg) {
                if (curg >= 0) {
                    atomicAdd(&psum[curg * 64 + t], s);
                    if (t == 0) atomicAdd(&cnt[curg], (float)rl);
                }
                s = 0.f; rl = 0; curg = gg;
            }
            if (gg >= 0) { s += rowsL[r * 68 + t]; ++rl; }
        }
        if (curg >= 0) {
            atomicAdd(&psum[curg * 64 + t], s);
            if (t == 0) atomicAdd(&cnt[curg], (float)rl);
        }
    }
}

// ---------------------------------------------------------------- head: mean + MLP (no binary search)
__global__ __launch_bounds__(64) void head_kernel(const float* __restrict__ psum,
                                                  const float* __restrict__ cnt,
                                                  const float* __restrict__ Wm1,
                                                  const float* __restrict__ bm1,
                                                  const float* __restrict__ Wm2,
                                                  const float* __restrict__ bm2,
                                                  float* __restrict__ out) {
    const int g = blockIdx.x;
    const int t = threadIdx.x;
    __shared__ float pl[64];
    const float inv = 1.f / fmaxf(cnt[g], 1.f);
    pl[t] = psum[g * 64 + t] * inv;
    __syncthreads();
    float z = bm1[t];
#pragma unroll 8
    for (int k = 0; k < 64; ++k)
        z += pl[k] * Wm1[k * 64 + t];
    z = fmaxf(z, 0.f);
    float y = z * Wm2[t];
    for (int off = 32; off; off >>= 1) y += __shfl_down(y, off);
    if (t == 0) out[g] = y + bm2[0];
}

// ---------------------------------------------------------------- launch
extern "C" void kernel_launch(void* const* d_in, const int* in_sizes, int n_in,
                              void* d_out, int out_size, void* d_ws, size_t ws_size,
                              hipStream_t stream) {
    const float* x   = (const float*)d_in[0];
    const int*   ei  = (const int*)d_in[1];
    const int*   bat = (const int*)d_in[2];
    const float* W1  = (const float*)d_in[3];
    const float* b1  = (const float*)d_in[4];
    const float* W2  = (const float*)d_in[5];
    const float* b2  = (const float*)d_in[6];
    const float* Wm1 = (const float*)d_in[7];
    const float* bm1 = (const float*)d_in[8];
    const float* Wm2 = (const float*)d_in[9];
    const float* bm2 = (const float*)d_in[10];
    float* out = (float*)d_out;

    char* w = (char*)d_ws;
    int*            histg     = (int*)           (w + 0);          //   153664 B
    int2*           row_range = (int2*)          (w + 153664);     //   400000 B
    float*          dis       = (float*)         (w + 553664);     //   200000 B
    int*            csr_src   = (int*)           (w + 753664);     //  4014080 B
    unsigned*       ebuf      = (unsigned*)      (w + 4767744);    // 12293120 B (packed 4B edges)
    unsigned short* bufA      = (unsigned short*)(w + 17060864);   //  6400000 B
    unsigned short* bufB      = (unsigned short*)(w + 23460864);   //  6400000 B
    float*          psum      = (float*)         (w + 29860864);   //    66560 B (16384 psum + 256 cnt)
    unsigned*       W2p       = (unsigned*)      (w + 29927424);   //     8192 B
    float*          cnt       = psum + 16384;

    prep_gemm <<<NC + NGB + 1, 256, 0, stream>>>(ei, histg, ebuf, x, W1, W2, bufA, psum, W2p);
    build_csr <<<NB, 512, 0, stream>>>(ebuf, histg, row_range, dis, csr_src);
    agg_gemv  <<<(NN + 31) / 32, 256, 0, stream>>>(bufA, row_range, csr_src, dis, b1, W2p, bufB);
    agg_pool  <<<(NN + 31) / 32, 256, 0, stream>>>(bufB, row_range, csr_src, dis, b2, bat, psum, cnt);
    head_kernel<<<NG, 64, 0, stream>>>(psum, cnt, Wm1, bm1, Wm2, bm2, out);
}